// Round 4
// baseline (292.054 us; speedup 1.0000x reference)
//
#include <hip/hip_runtime.h>
#include <hip/hip_bf16.h>

typedef __attribute__((ext_vector_type(8))) short short8;
typedef __attribute__((ext_vector_type(4))) float f32x4;

#define NB 4
#define NN 9216
#define NM 2304

__device__ inline unsigned pk2(float a, float b) {
  __hip_bfloat16 ha = __float2bfloat16(a), hb = __float2bfloat16(b);
  return (unsigned)*(unsigned short*)&ha | ((unsigned)*(unsigned short*)&hb << 16);
}
__device__ inline short8 pack8(const float* v) {
  short8 s;
#pragma unroll
  for (int j = 0; j < 8; ++j) { __hip_bfloat16 h = __float2bfloat16(v[j]); s[j] = *(short*)&h; }
  return s;
}
__device__ inline short8 ldw8(const float* p) {  // 8 fp32 -> bf16 frag
  float tmp[8];
  *(float4*)&tmp[0] = *(const float4*)p;
  *(float4*)&tmp[4] = *(const float4*)(p + 4);
  return pack8(tmp);
}

// ---------------------------------------------------------------------------
// Fused conv1x1 (theta,g,phi) + 2x2 maxpool for g/phi.
// grid (3*48, B), block 128 (2 waves). Wave covers rows i0,i0+1 x 16 cols.
// Outputs: Theta [B][N][64], Gcm [B][64][M], PhiT [B][M][64]  (bf16).
// Also zeroes psum (BN stats accumulator used by attn_k).
// ---------------------------------------------------------------------------
__global__ __launch_bounds__(128) void conv_pool_k(
    const float* __restrict__ x, const float* __restrict__ feat,
    const float* __restrict__ tw, const float* __restrict__ tbi,
    const float* __restrict__ gw, const float* __restrict__ gbi,
    const float* __restrict__ pw, const float* __restrict__ pbi,
    __hip_bfloat16* __restrict__ Theta, __hip_bfloat16* __restrict__ Gcm,
    __hip_bfloat16* __restrict__ PhiT, float* __restrict__ psum) {
  int t = threadIdx.x, wv = t >> 6, lane = t & 63, l15 = lane & 15, q = lane >> 4;
  int b = blockIdx.y, bx = blockIdx.x;
  if (bx == 0 && b == 0 && t < 64) psum[t] = 0.f;
  int jt = bx % 3, rp = bx / 3;          // jt 0..2, rp 0..47
  int i0 = rp * 2;
  int j0 = jt * 32 + wv * 16;
  int ntop = i0 * 96 + j0;

  // weight A-frags: A[o=ot*16+l15][k=c=kf*32+q*8+j]  (L2-hot, same for all waves)
  short8 wt[4][2], wg[4][2], wp[4];
#pragma unroll
  for (int ot = 0; ot < 4; ++ot) {
#pragma unroll
    for (int kf = 0; kf < 2; ++kf) {
      wt[ot][kf] = ldw8(tw + (size_t)(ot * 16 + l15) * 64 + kf * 32 + q * 8);
      wg[ot][kf] = ldw8(gw + (size_t)(ot * 16 + l15) * 64 + kf * 32 + q * 8);
    }
    wp[ot] = ldw8(pw + (size_t)(ot * 16 + l15) * 32 + q * 8);
  }

  // input B-frags: B[k=c][n=l15], rows i0 (row=0) and i0+1 (row=1)
  short8 bxf[2][2], bff[2];
  {
    float tmp[8];
#pragma unroll
    for (int row = 0; row < 2; ++row) {
#pragma unroll
      for (int kf = 0; kf < 2; ++kf) {
#pragma unroll
        for (int j = 0; j < 8; ++j)
          tmp[j] = x[((size_t)b * 64 + kf * 32 + q * 8 + j) * NN + ntop + row * 96 + l15];
        bxf[row][kf] = pack8(tmp);
      }
#pragma unroll
      for (int j = 0; j < 8; ++j)
        tmp[j] = feat[((size_t)b * 32 + q * 8 + j) * NN + ntop + row * 96 + l15];
      bff[row] = pack8(tmp);
    }
  }

  int m = (i0 >> 1) * 48 + ((j0 + l15) >> 1);
  bool em = (l15 & 1) == 0;

#pragma unroll
  for (int ot = 0; ot < 4; ++ot) {
    // ---- theta (unpooled), both rows ----
#pragma unroll
    for (int row = 0; row < 2; ++row) {
      f32x4 d;
#pragma unroll
      for (int r = 0; r < 4; ++r) d[r] = tbi[ot * 16 + q * 4 + r];
      d = __builtin_amdgcn_mfma_f32_16x16x32_bf16(wt[ot][0], bxf[row][0], d, 0, 0, 0);
      d = __builtin_amdgcn_mfma_f32_16x16x32_bf16(wt[ot][1], bxf[row][1], d, 0, 0, 0);
      size_t base = ((size_t)b * NN + ntop + row * 96 + l15) * 64 + ot * 16 + q * 4;
      *(unsigned*)(Theta + base) = pk2(d[0], d[1]);
      *(unsigned*)(Theta + base + 2) = pk2(d[2], d[3]);
    }
    // ---- g: conv both rows, 2x2 max, -> Gcm [c][m] ----
    {
      f32x4 d0, d1;
#pragma unroll
      for (int r = 0; r < 4; ++r) { float bb = gbi[ot * 16 + q * 4 + r]; d0[r] = bb; d1[r] = bb; }
      d0 = __builtin_amdgcn_mfma_f32_16x16x32_bf16(wg[ot][0], bxf[0][0], d0, 0, 0, 0);
      d0 = __builtin_amdgcn_mfma_f32_16x16x32_bf16(wg[ot][1], bxf[0][1], d0, 0, 0, 0);
      d1 = __builtin_amdgcn_mfma_f32_16x16x32_bf16(wg[ot][0], bxf[1][0], d1, 0, 0, 0);
      d1 = __builtin_amdgcn_mfma_f32_16x16x32_bf16(wg[ot][1], bxf[1][1], d1, 0, 0, 0);
      float h[4];
#pragma unroll
      for (int r = 0; r < 4; ++r) {
        float v = fmaxf(d0[r], d1[r]);
        h[r] = fmaxf(v, __shfl_xor(v, 1));   // horizontal pair max (cols l15, l15^1)
      }
      if (em) {
#pragma unroll
        for (int r = 0; r < 4; ++r)
          Gcm[((size_t)b * 64 + ot * 16 + q * 4 + r) * NM + m] = __float2bfloat16(h[r]);
      }
    }
    // ---- phi: conv(feature) both rows, 2x2 max, -> PhiT [m][c] ----
    {
      f32x4 d0, d1;
#pragma unroll
      for (int r = 0; r < 4; ++r) { float bb = pbi[ot * 16 + q * 4 + r]; d0[r] = bb; d1[r] = bb; }
      d0 = __builtin_amdgcn_mfma_f32_16x16x32_bf16(wp[ot], bff[0], d0, 0, 0, 0);
      d1 = __builtin_amdgcn_mfma_f32_16x16x32_bf16(wp[ot], bff[1], d1, 0, 0, 0);
      float h[4];
#pragma unroll
      for (int r = 0; r < 4; ++r) {
        float v = fmaxf(d0[r], d1[r]);
        h[r] = fmaxf(v, __shfl_xor(v, 1));
      }
      if (em) {
        size_t base = ((size_t)b * NM + m) * 64 + ot * 16 + q * 4;
        *(unsigned*)(PhiT + base) = pk2(h[0], h[1]);
        *(unsigned*)(PhiT + base + 2) = pk2(h[2], h[3]);
      }
    }
  }
}

// ---------------------------------------------------------------------------
// Fused attention + residual + W-conv + BN-stats.  grid (144, B), block 256.
// Waves split over n (16 rows each, full M sweep); frags direct from global
// (PhiT/Gcm are 294 KB/batch -> L1/L2-hot). No barriers in main loop.
// z2 [B][N][32] fp32; psum[0..31]=sum, psum[32..63]=sumsq (atomic).
// ---------------------------------------------------------------------------
__global__ __launch_bounds__(256) void attn_k(
    const __hip_bfloat16* __restrict__ Theta, const __hip_bfloat16* __restrict__ PhiT,
    const __hip_bfloat16* __restrict__ Gcm, const float* __restrict__ x,
    const float* __restrict__ Ww, const float* __restrict__ Wb,
    float* __restrict__ z2, float* __restrict__ psum) {
  __shared__ union {
    __hip_bfloat16 pbuf[4][16][40];   // per-wave P tile [n][m], main loop
    __hip_bfloat16 zacc[64][72];      // z1 bf16 [n][c], epilogue
  } u;
  __shared__ float rs[4][64];         // BN-stats cross-wave buffer

  int t = threadIdx.x;
  int wv = t >> 6, lane = t & 63;
  int l15 = lane & 15, q = lane >> 4;
  int b = blockIdx.y;
  int n0 = blockIdx.x * 64;
  int nw = n0 + wv * 16;              // this wave's 16 n-rows

  // Theta B-frags: B[k=c][n=l15]
  short8 tbf[2];
#pragma unroll
  for (int kf = 0; kf < 2; ++kf)
    tbf[kf] = *(const short8*)(Theta + ((size_t)b * NN + nw + l15) * 64 + kf * 32 + q * 8);

  f32x4 acc[4];
#pragma unroll
  for (int ct = 0; ct < 4; ++ct) acc[ct] = (f32x4){0.f, 0.f, 0.f, 0.f};
  float rsum = 0.f;

  const __hip_bfloat16* phib = PhiT + (size_t)b * NM * 64;
  const __hip_bfloat16* gbb  = Gcm + (size_t)b * 64 * NM;

#pragma unroll 2
  for (int ck = 0; ck < 72; ++ck) {
    int m0 = ck * 32;
    // Phi A-frags: A[m=l15(+16)][k=c]
    const __hip_bfloat16* pr = phib + (size_t)(m0 + l15) * 64 + q * 8;
    short8 pa00 = *(const short8*)pr;
    short8 pa01 = *(const short8*)(pr + 32);
    short8 pa10 = *(const short8*)(pr + 16 * 64);
    short8 pa11 = *(const short8*)(pr + 16 * 64 + 32);
    // G B-frags: B[k=m][n=c=ct*16+l15]
    short8 g0 = *(const short8*)(gbb + (size_t)(l15) * NM + m0 + q * 8);
    short8 g1 = *(const short8*)(gbb + (size_t)(16 + l15) * NM + m0 + q * 8);
    short8 g2 = *(const short8*)(gbb + (size_t)(32 + l15) * NM + m0 + q * 8);
    short8 g3 = *(const short8*)(gbb + (size_t)(48 + l15) * NM + m0 + q * 8);

    // S^T tiles: D[m][n], row m=q*4+r, col n=l15
    f32x4 s0 = (f32x4){0.f, 0.f, 0.f, 0.f};
    s0 = __builtin_amdgcn_mfma_f32_16x16x32_bf16(pa00, tbf[0], s0, 0, 0, 0);
    s0 = __builtin_amdgcn_mfma_f32_16x16x32_bf16(pa01, tbf[1], s0, 0, 0, 0);
    f32x4 s1 = (f32x4){0.f, 0.f, 0.f, 0.f};
    s1 = __builtin_amdgcn_mfma_f32_16x16x32_bf16(pa10, tbf[0], s1, 0, 0, 0);
    s1 = __builtin_amdgcn_mfma_f32_16x16x32_bf16(pa11, tbf[1], s1, 0, 0, 0);

    float e0 = __expf(s0[0]), e1 = __expf(s0[1]), e2 = __expf(s0[2]), e3 = __expf(s0[3]);
    rsum += (e0 + e1) + (e2 + e3);
    unsigned* pb0 = (unsigned*)&u.pbuf[wv][l15][q * 4];
    pb0[0] = pk2(e0, e1);
    pb0[1] = pk2(e2, e3);
    float f0 = __expf(s1[0]), f1 = __expf(s1[1]), f2 = __expf(s1[2]), f3 = __expf(s1[3]);
    rsum += (f0 + f1) + (f2 + f3);
    unsigned* pb1 = (unsigned*)&u.pbuf[wv][l15][16 + q * 4];
    pb1[0] = pk2(f0, f1);
    pb1[1] = pk2(f2, f3);

    // PV: A = P[n=l15][k=m=q*8+j]  (wave-local round trip)
    short8 pf = *(const short8*)&u.pbuf[wv][l15][q * 8];
    acc[0] = __builtin_amdgcn_mfma_f32_16x16x32_bf16(pf, g0, acc[0], 0, 0, 0);
    acc[1] = __builtin_amdgcn_mfma_f32_16x16x32_bf16(pf, g1, acc[1], 0, 0, 0);
    acc[2] = __builtin_amdgcn_mfma_f32_16x16x32_bf16(pf, g2, acc[2], 0, 0, 0);
    acc[3] = __builtin_amdgcn_mfma_f32_16x16x32_bf16(pf, g3, acc[3], 0, 0, 0);
  }

  // rowsum (intra-wave only: reduce over q), n = nw + l15
  float v = rsum;
  v += __shfl_xor(v, 16);
  v += __shfl_xor(v, 32);
  float rinv = 1.0f / v;
  float riv[4];
#pragma unroll
  for (int r = 0; r < 4; ++r) riv[r] = __shfl(rinv, q * 4 + r);  // inverse for row q*4+r

  __syncthreads();  // all waves done with pbuf (zacc aliases it)

  // z1 = y*rinv + x -> zacc[n][c] bf16   (PV D-layout: row n=q*4+r, col c=ct*16+l15)
#pragma unroll
  for (int ct = 0; ct < 4; ++ct) {
#pragma unroll
    for (int r = 0; r < 4; ++r) {
      float xv = x[((size_t)b * 64 + ct * 16 + l15) * NN + nw + q * 4 + r];
      u.zacc[wv * 16 + q * 4 + r][ct * 16 + l15] =
          __float2bfloat16(acc[ct][r] * riv[r] + xv);
    }
  }
  __syncthreads();

  // W-conv: z2[n][o] = zacc[n][:]·Ww^T + Wb   (A = zacc rows n, B = Ww cols o)
  short8 wbf[2][2];
#pragma unroll
  for (int ot = 0; ot < 2; ++ot)
#pragma unroll
    for (int kf = 0; kf < 2; ++kf)
      wbf[ot][kf] = ldw8(Ww + (size_t)(ot * 16 + l15) * 64 + kf * 32 + q * 8);
  short8 za0 = *(const short8*)&u.zacc[wv * 16 + l15][q * 8];
  short8 za1 = *(const short8*)&u.zacc[wv * 16 + l15][32 + q * 8];

  f32x4 dd[2];
#pragma unroll
  for (int ot = 0; ot < 2; ++ot) {
    float bias = Wb[ot * 16 + l15];
    f32x4 d = (f32x4){bias, bias, bias, bias};
    d = __builtin_amdgcn_mfma_f32_16x16x32_bf16(za0, wbf[ot][0], d, 0, 0, 0);
    d = __builtin_amdgcn_mfma_f32_16x16x32_bf16(za1, wbf[ot][1], d, 0, 0, 0);
#pragma unroll
    for (int r = 0; r < 4; ++r)
      z2[((size_t)b * NN + n0 + wv * 16 + q * 4 + r) * 32 + ot * 16 + l15] = d[r];
    dd[ot] = d;
  }

  // BN stats: per-block partial sums -> 64 global atomics
#pragma unroll
  for (int ot = 0; ot < 2; ++ot) {
    float ps = (dd[ot][0] + dd[ot][1]) + (dd[ot][2] + dd[ot][3]);
    float ps2 = dd[ot][0] * dd[ot][0] + dd[ot][1] * dd[ot][1] +
                dd[ot][2] * dd[ot][2] + dd[ot][3] * dd[ot][3];
    ps += __shfl_xor(ps, 16);  ps += __shfl_xor(ps, 32);
    ps2 += __shfl_xor(ps2, 16); ps2 += __shfl_xor(ps2, 32);
    if (lane < 16) {
      rs[wv][ot * 16 + lane] = ps;
      rs[wv][32 + ot * 16 + lane] = ps2;
    }
  }
  __syncthreads();
  if (t < 64) {
    float tot = rs[0][t] + rs[1][t] + rs[2][t] + rs[3][t];
    atomicAdd(&psum[t], tot);
  }
}

// ---------------------------------------------------------------------------
// BN finalize (per-block from psum) + apply + transpose [n][32] -> [32][n].
// ---------------------------------------------------------------------------
__global__ __launch_bounds__(256) void bn_apply(
    const float* __restrict__ z2, const float* __restrict__ psum,
    const float* __restrict__ gamma, const float* __restrict__ beta,
    float* __restrict__ out) {
  __shared__ float ssl[64];
  __shared__ float zt[32][65];
  int t = threadIdx.x, b = blockIdx.y, n0 = blockIdx.x * 64;
  if (t < 32) {
    const float inv = 1.0f / (float)(NB * NN);
    float mean = psum[t] * inv;
    float var = psum[32 + t] * inv - mean * mean;
    float sc = gamma[t] * rsqrtf(var + 1e-5f);
    ssl[t] = sc;
    ssl[32 + t] = beta[t] - mean * sc;
  }
#pragma unroll
  for (int it = 0; it < 2; ++it) {
    int idx = it * 256 + t, r = idx >> 3, seg = idx & 7;
    float4 vv = *(const float4*)(z2 + ((size_t)b * NN + n0 + r) * 32 + seg * 4);
    zt[seg * 4 + 0][r] = vv.x; zt[seg * 4 + 1][r] = vv.y;
    zt[seg * 4 + 2][r] = vv.z; zt[seg * 4 + 3][r] = vv.w;
  }
  __syncthreads();
  int o = t >> 3, nseg = t & 7;
  float sc = ssl[o], sh = ssl[32 + o];
  float4 a, c;
  a.x = zt[o][nseg * 8 + 0] * sc + sh; a.y = zt[o][nseg * 8 + 1] * sc + sh;
  a.z = zt[o][nseg * 8 + 2] * sc + sh; a.w = zt[o][nseg * 8 + 3] * sc + sh;
  c.x = zt[o][nseg * 8 + 4] * sc + sh; c.y = zt[o][nseg * 8 + 5] * sc + sh;
  c.z = zt[o][nseg * 8 + 6] * sc + sh; c.w = zt[o][nseg * 8 + 7] * sc + sh;
  float* po = out + ((size_t)b * 32 + o) * NN + n0 + nseg * 8;
  *(float4*)po = a;
  *(float4*)(po + 4) = c;
}

// ---------------------------------------------------------------------------
extern "C" void kernel_launch(void* const* d_in, const int* in_sizes, int n_in,
                              void* d_out, int out_size, void* d_ws, size_t ws_size,
                              hipStream_t stream) {
  const float* x       = (const float*)d_in[0];
  const float* feature = (const float*)d_in[1];
  const float* g_w     = (const float*)d_in[2];
  const float* g_b     = (const float*)d_in[3];
  const float* theta_w = (const float*)d_in[4];
  const float* theta_b = (const float*)d_in[5];
  const float* phi_w   = (const float*)d_in[6];
  const float* phi_b   = (const float*)d_in[7];
  const float* W_w     = (const float*)d_in[8];
  const float* W_b     = (const float*)d_in[9];
  const float* bn_g    = (const float*)d_in[10];
  const float* bn_b    = (const float*)d_in[11];

  char* ws = (char*)d_ws;
  const size_t szTheta = (size_t)NB * NN * 64 * sizeof(__hip_bfloat16);  // 4,718,592
  const size_t szM     = (size_t)NB * 64 * NM * sizeof(__hip_bfloat16); // 1,179,648
  __hip_bfloat16* Theta = (__hip_bfloat16*)(ws);
  __hip_bfloat16* Gcm   = (__hip_bfloat16*)(ws + szTheta);
  __hip_bfloat16* PhiT  = (__hip_bfloat16*)(ws + szTheta + szM);
  float*          z2    = (float*)(ws + szTheta + 2 * szM);              // [B][N][32] fp32
  float*          psum  = (float*)(ws + szTheta + 2 * szM +
                                   (size_t)NB * NN * 32 * sizeof(float));

  conv_pool_k<<<dim3(144, NB), dim3(128), 0, stream>>>(
      x, feature, theta_w, theta_b, g_w, g_b, phi_w, phi_b, Theta, Gcm, PhiT, psum);
  attn_k<<<dim3(NN / 64, NB), dim3(256), 0, stream>>>(
      Theta, PhiT, Gcm, x, W_w, W_b, z2, psum);
  bn_apply<<<dim3(NN / 64, NB), dim3(256), 0, stream>>>(
      z2, psum, bn_g, bn_b, (float*)d_out);
}

// Round 5
// 165.169 us; speedup vs baseline: 1.7682x; 1.7682x over previous
//
#include <hip/hip_runtime.h>
#include <hip/hip_bf16.h>

typedef __attribute__((ext_vector_type(8))) short short8;
typedef __attribute__((ext_vector_type(4))) float f32x4;

#define NB 4
#define NN 9216
#define NM 2304
#define MSPLIT 4
#define MSL (NM / MSPLIT)   // 576

__device__ inline unsigned pk2(float a, float b) {
  __hip_bfloat16 ha = __float2bfloat16(a), hb = __float2bfloat16(b);
  return (unsigned)*(unsigned short*)&ha | ((unsigned)*(unsigned short*)&hb << 16);
}
__device__ inline float b2f(short s) {
  unsigned u = ((unsigned)(unsigned short)s) << 16; return *(float*)&u;
}
__device__ inline short8 pack8(const float* v) {
  short8 s;
#pragma unroll
  for (int j = 0; j < 8; ++j) { __hip_bfloat16 h = __float2bfloat16(v[j]); s[j] = *(short*)&h; }
  return s;
}
__device__ inline short8 ldw8(const float* p) {
  float tmp[8];
  *(float4*)&tmp[0] = *(const float4*)p;
  *(float4*)&tmp[4] = *(const float4*)(p + 4);
  return pack8(tmp);
}

// ---------------------------------------------------------------------------
// Fused conv1x1 (theta,g,phi) + 2x2 maxpool for g/phi.  r4-verified mappings,
// restructured: 4 waves = 4 ot slices, block covers row-pair rp x 16 cols.
// grid (288, B) x 256.  1152 blocks (vs 576x2-wave) -> 18 waves/CU.
// ---------------------------------------------------------------------------
__global__ __launch_bounds__(256) void conv_pool_k(
    const float* __restrict__ x, const float* __restrict__ feat,
    const float* __restrict__ tw, const float* __restrict__ tbi,
    const float* __restrict__ gw, const float* __restrict__ gbi,
    const float* __restrict__ pw, const float* __restrict__ pbi,
    __hip_bfloat16* __restrict__ Theta, __hip_bfloat16* __restrict__ Gcm,
    __hip_bfloat16* __restrict__ PhiT, float* __restrict__ psum) {
  int t = threadIdx.x, wv = t >> 6, lane = t & 63, l15 = lane & 15, q = lane >> 4;
  int b = blockIdx.y, bx = blockIdx.x;
  if (bx == 0 && b == 0 && t < 64) psum[t] = 0.f;
  int jt = bx % 6, rp = bx / 6;
  int i0 = rp * 2, j0 = jt * 16;
  int ntop = i0 * 96 + j0;
  int ot = wv;   // wave owns one 16-wide output slice

  // weights for this ot: A[o=ot*16+l15][k=c]
  short8 wt[2], wg[2], wp1;
#pragma unroll
  for (int kf = 0; kf < 2; ++kf) {
    wt[kf] = ldw8(tw + (size_t)(ot * 16 + l15) * 64 + kf * 32 + q * 8);
    wg[kf] = ldw8(gw + (size_t)(ot * 16 + l15) * 64 + kf * 32 + q * 8);
  }
  wp1 = ldw8(pw + (size_t)(ot * 16 + l15) * 32 + q * 8);

  // input B-frags: B[k=c][n=l15], rows i0, i0+1
  short8 bxf[2][2], bff[2];
  {
    float tmp[8];
#pragma unroll
    for (int row = 0; row < 2; ++row) {
#pragma unroll
      for (int kf = 0; kf < 2; ++kf) {
#pragma unroll
        for (int j = 0; j < 8; ++j)
          tmp[j] = x[((size_t)b * 64 + kf * 32 + q * 8 + j) * NN + ntop + row * 96 + l15];
        bxf[row][kf] = pack8(tmp);
      }
#pragma unroll
      for (int j = 0; j < 8; ++j)
        tmp[j] = feat[((size_t)b * 32 + q * 8 + j) * NN + ntop + row * 96 + l15];
      bff[row] = pack8(tmp);
    }
  }

  int m = rp * 48 + ((j0 + l15) >> 1);
  bool em = (l15 & 1) == 0;

  // ---- theta (unpooled), both rows ----
#pragma unroll
  for (int row = 0; row < 2; ++row) {
    f32x4 d;
#pragma unroll
    for (int r = 0; r < 4; ++r) d[r] = tbi[ot * 16 + q * 4 + r];
    d = __builtin_amdgcn_mfma_f32_16x16x32_bf16(wt[0], bxf[row][0], d, 0, 0, 0);
    d = __builtin_amdgcn_mfma_f32_16x16x32_bf16(wt[1], bxf[row][1], d, 0, 0, 0);
    size_t base = ((size_t)b * NN + ntop + row * 96 + l15) * 64 + ot * 16 + q * 4;
    *(unsigned*)(Theta + base) = pk2(d[0], d[1]);
    *(unsigned*)(Theta + base + 2) = pk2(d[2], d[3]);
  }
  // ---- g: conv both rows, 2x2 max -> Gcm [c][m] ----
  {
    f32x4 d0, d1;
#pragma unroll
    for (int r = 0; r < 4; ++r) { float bb = gbi[ot * 16 + q * 4 + r]; d0[r] = bb; d1[r] = bb; }
    d0 = __builtin_amdgcn_mfma_f32_16x16x32_bf16(wg[0], bxf[0][0], d0, 0, 0, 0);
    d0 = __builtin_amdgcn_mfma_f32_16x16x32_bf16(wg[1], bxf[0][1], d0, 0, 0, 0);
    d1 = __builtin_amdgcn_mfma_f32_16x16x32_bf16(wg[0], bxf[1][0], d1, 0, 0, 0);
    d1 = __builtin_amdgcn_mfma_f32_16x16x32_bf16(wg[1], bxf[1][1], d1, 0, 0, 0);
    float h[4];
#pragma unroll
    for (int r = 0; r < 4; ++r) {
      float v = fmaxf(d0[r], d1[r]);
      h[r] = fmaxf(v, __shfl_xor(v, 1));
    }
    if (em) {
#pragma unroll
      for (int r = 0; r < 4; ++r)
        Gcm[((size_t)b * 64 + ot * 16 + q * 4 + r) * NM + m] = __float2bfloat16(h[r]);
    }
  }
  // ---- phi: conv(feature) both rows, 2x2 max -> PhiT [m][c] ----
  {
    f32x4 d0, d1;
#pragma unroll
    for (int r = 0; r < 4; ++r) { float bb = pbi[ot * 16 + q * 4 + r]; d0[r] = bb; d1[r] = bb; }
    d0 = __builtin_amdgcn_mfma_f32_16x16x32_bf16(wp1, bff[0], d0, 0, 0, 0);
    d1 = __builtin_amdgcn_mfma_f32_16x16x32_bf16(wp1, bff[1], d1, 0, 0, 0);
    float h[4];
#pragma unroll
    for (int r = 0; r < 4; ++r) {
      float v = fmaxf(d0[r], d1[r]);
      h[r] = fmaxf(v, __shfl_xor(v, 1));
    }
    if (em) {
      size_t base = ((size_t)b * NM + m) * 64 + ot * 16 + q * 4;
      *(unsigned*)(PhiT + base) = pk2(h[0], h[1]);
      *(unsigned*)(PhiT + base + 2) = pk2(h[2], h[3]);
    }
  }
}

// ---------------------------------------------------------------------------
// Attention partial: r2-verified LDS-staged structure over an M-slice.
// grid (576, B): nb = bx%144 (n-tile), split = bx/144 (M-slice).  block 256.
// Emits unscaled ypart [split][b][n][64] bf16 and rsumpart [split][b][n] f32.
// ---------------------------------------------------------------------------
__global__ __launch_bounds__(256) void attn_part(
    const __hip_bfloat16* __restrict__ Theta, const __hip_bfloat16* __restrict__ PhiT,
    const __hip_bfloat16* __restrict__ Gcm,
    __hip_bfloat16* __restrict__ ypart, float* __restrict__ rsumpart) {
  __shared__ __align__(16) __hip_bfloat16 phis[32][72];    // [m][c]
  __shared__ __align__(16) __hip_bfloat16 gs[64][40];      // [c][m]
  __shared__ __align__(16) __hip_bfloat16 pbuf[4][16][40]; // per-wave P [n][m]

  int t = threadIdx.x, wv = t >> 6, lane = t & 63;
  int l15 = lane & 15, q = lane >> 4;
  int bx = blockIdx.x;
  int nb = bx % 144, split = bx / 144;
  int b = blockIdx.y;
  int n0 = nb * 64, nw = n0 + wv * 16;
  int mbase = split * MSL;

  // Theta A-frags: A[m=n-row=l15][k=c=q*8+j]
  const __hip_bfloat16* trow = Theta + ((size_t)b * NN + nw + l15) * 64 + q * 8;
  short8 ta0 = *(const short8*)trow;
  short8 ta1 = *(const short8*)(trow + 32);

  f32x4 acc[4];
#pragma unroll
  for (int ct = 0; ct < 4; ++ct) acc[ct] = (f32x4){0.f, 0.f, 0.f, 0.f};
  float rsum[4] = {0.f, 0.f, 0.f, 0.f};

  const __hip_bfloat16* phibase = PhiT + (size_t)b * NM * 64;
  const __hip_bfloat16* gbase = Gcm + (size_t)b * 64 * NM;

  for (int ck = 0; ck < MSL / 32; ++ck) {   // 18 chunks
    int m0 = mbase + ck * 32;
    __syncthreads();
    {   // stage Phi chunk: 32 m-rows x 64 c
      int r = t >> 3, seg = t & 7;
      *(uint4*)&phis[r][seg * 8] = *(const uint4*)(phibase + (size_t)(m0 + r) * 64 + seg * 8);
    }
    {   // stage G chunk: 64 c-rows x 32 m
      int r = t >> 2, seg = t & 3;
      *(uint4*)&gs[r][seg * 8] = *(const uint4*)(gbase + (size_t)r * NM + m0 + seg * 8);
    }
    __syncthreads();

#pragma unroll
    for (int tm = 0; tm < 2; ++tm) {
      // B-frag: B[k=c=q*8+j][n(col)=m=tm*16+l15]
      short8 pb0 = *(const short8*)&phis[tm * 16 + l15][q * 8];
      short8 pb1 = *(const short8*)&phis[tm * 16 + l15][32 + q * 8];
      f32x4 s = (f32x4){0.f, 0.f, 0.f, 0.f};
      s = __builtin_amdgcn_mfma_f32_16x16x32_bf16(ta0, pb0, s, 0, 0, 0);
      s = __builtin_amdgcn_mfma_f32_16x16x32_bf16(ta1, pb1, s, 0, 0, 0);
      // D: row n=q*4+r, col m=tm*16+l15
#pragma unroll
      for (int r = 0; r < 4; ++r) {
        float e = __expf(s[r]);
        rsum[r] += e;
        pbuf[wv][q * 4 + r][tm * 16 + l15] = __float2bfloat16(e);
      }
    }
    // PV: A = P[n=l15][k=m=q*8+j]
    short8 pa = *(const short8*)&pbuf[wv][l15][q * 8];
#pragma unroll
    for (int ct = 0; ct < 4; ++ct) {
      short8 gb = *(const short8*)&gs[ct * 16 + l15][q * 8];  // B[k=m][n=c]
      acc[ct] = __builtin_amdgcn_mfma_f32_16x16x32_bf16(pa, gb, acc[ct], 0, 0, 0);
    }
  }

  // partial rowsum: reduce over the 16 m-lanes
#pragma unroll
  for (int r = 0; r < 4; ++r) {
    float v = rsum[r];
    v += __shfl_xor(v, 1); v += __shfl_xor(v, 2);
    v += __shfl_xor(v, 4); v += __shfl_xor(v, 8);
    if (l15 == 0)
      rsumpart[(size_t)(split * NB + b) * NN + nw + q * 4 + r] = v;
  }
  // partial y (unscaled) -> ypart bf16
#pragma unroll
  for (int ct = 0; ct < 4; ++ct)
#pragma unroll
    for (int r = 0; r < 4; ++r)
      ypart[((size_t)(split * NB + b) * NN + nw + q * 4 + r) * 64 + ct * 16 + l15] =
          __float2bfloat16(acc[ct][r]);
}

// ---------------------------------------------------------------------------
// Combine partials + residual + W-conv (MFMA) + BN stats.
// grid (144, B) x 256; wave = 16 n-rows; A-frags built in registers.
// ---------------------------------------------------------------------------
__global__ __launch_bounds__(256) void combine_k(
    const __hip_bfloat16* __restrict__ ypart, const float* __restrict__ rsumpart,
    const float* __restrict__ x, const float* __restrict__ Ww, const float* __restrict__ Wb,
    float* __restrict__ z2, float* __restrict__ psum) {
  __shared__ float rs[4][64];
  int t = threadIdx.x, wv = t >> 6, lane = t & 63;
  int l15 = lane & 15, q = lane >> 4;
  int b = blockIdx.y, n0 = blockIdx.x * 64, nw = n0 + wv * 16;
  int nrow = nw + l15;

  float y0[8], y1[8];
#pragma unroll
  for (int j = 0; j < 8; ++j) { y0[j] = 0.f; y1[j] = 0.f; }
  float rsum = 0.f;
#pragma unroll
  for (int s = 0; s < MSPLIT; ++s) {
    const __hip_bfloat16* yp = ypart + ((size_t)(s * NB + b) * NN + nrow) * 64;
    short8 a = *(const short8*)(yp + q * 8);
    short8 c = *(const short8*)(yp + 32 + q * 8);
#pragma unroll
    for (int j = 0; j < 8; ++j) { y0[j] += b2f(a[j]); y1[j] += b2f(c[j]); }
    rsum += rsumpart[(size_t)(s * NB + b) * NN + nrow];
  }
  float rinv = 1.0f / rsum;

  float z1a[8], z1b[8];
#pragma unroll
  for (int j = 0; j < 8; ++j) {
    z1a[j] = y0[j] * rinv + x[((size_t)b * 64 + q * 8 + j) * NN + nrow];
    z1b[j] = y1[j] * rinv + x[((size_t)b * 64 + 32 + q * 8 + j) * NN + nrow];
  }
  short8 za0 = pack8(z1a), za1 = pack8(z1b);  // A[m=n-row=l15][k=c]

  short8 wbf[2][2];
#pragma unroll
  for (int ot = 0; ot < 2; ++ot)
#pragma unroll
    for (int kf = 0; kf < 2; ++kf)
      wbf[ot][kf] = ldw8(Ww + (size_t)(ot * 16 + l15) * 64 + kf * 32 + q * 8);

  f32x4 dd[2];
#pragma unroll
  for (int ot = 0; ot < 2; ++ot) {
    float bias = Wb[ot * 16 + l15];
    f32x4 d = (f32x4){bias, bias, bias, bias};
    d = __builtin_amdgcn_mfma_f32_16x16x32_bf16(za0, wbf[ot][0], d, 0, 0, 0);
    d = __builtin_amdgcn_mfma_f32_16x16x32_bf16(za1, wbf[ot][1], d, 0, 0, 0);
#pragma unroll
    for (int r = 0; r < 4; ++r)
      z2[((size_t)b * NN + nw + q * 4 + r) * 32 + ot * 16 + l15] = d[r];
    dd[ot] = d;
  }

  // BN stats tail
#pragma unroll
  for (int ot = 0; ot < 2; ++ot) {
    float ps = (dd[ot][0] + dd[ot][1]) + (dd[ot][2] + dd[ot][3]);
    float ps2 = dd[ot][0] * dd[ot][0] + dd[ot][1] * dd[ot][1] +
                dd[ot][2] * dd[ot][2] + dd[ot][3] * dd[ot][3];
    ps += __shfl_xor(ps, 16);  ps += __shfl_xor(ps, 32);
    ps2 += __shfl_xor(ps2, 16); ps2 += __shfl_xor(ps2, 32);
    if (lane < 16) {
      rs[wv][ot * 16 + lane] = ps;
      rs[wv][32 + ot * 16 + lane] = ps2;
    }
  }
  __syncthreads();
  if (t < 64) {
    float tot = rs[0][t] + rs[1][t] + rs[2][t] + rs[3][t];
    atomicAdd(&psum[t], tot);
  }
}

// ---------------------------------------------------------------------------
// BN finalize + apply + transpose [n][32] -> [32][n].
// ---------------------------------------------------------------------------
__global__ __launch_bounds__(256) void bn_apply(
    const float* __restrict__ z2, const float* __restrict__ psum,
    const float* __restrict__ gamma, const float* __restrict__ beta,
    float* __restrict__ out) {
  __shared__ float ssl[64];
  __shared__ float zt[32][65];
  int t = threadIdx.x, b = blockIdx.y, n0 = blockIdx.x * 64;
  if (t < 32) {
    const float inv = 1.0f / (float)(NB * NN);
    float mean = psum[t] * inv;
    float var = psum[32 + t] * inv - mean * mean;
    float sc = gamma[t] * rsqrtf(var + 1e-5f);
    ssl[t] = sc;
    ssl[32 + t] = beta[t] - mean * sc;
  }
#pragma unroll
  for (int it = 0; it < 2; ++it) {
    int idx = it * 256 + t, r = idx >> 3, seg = idx & 7;
    float4 vv = *(const float4*)(z2 + ((size_t)b * NN + n0 + r) * 32 + seg * 4);
    zt[seg * 4 + 0][r] = vv.x; zt[seg * 4 + 1][r] = vv.y;
    zt[seg * 4 + 2][r] = vv.z; zt[seg * 4 + 3][r] = vv.w;
  }
  __syncthreads();
  int o = t >> 3, nseg = t & 7;
  float sc = ssl[o], sh = ssl[32 + o];
  float4 a, c;
  a.x = zt[o][nseg * 8 + 0] * sc + sh; a.y = zt[o][nseg * 8 + 1] * sc + sh;
  a.z = zt[o][nseg * 8 + 2] * sc + sh; a.w = zt[o][nseg * 8 + 3] * sc + sh;
  c.x = zt[o][nseg * 8 + 4] * sc + sh; c.y = zt[o][nseg * 8 + 5] * sc + sh;
  c.z = zt[o][nseg * 8 + 6] * sc + sh; c.w = zt[o][nseg * 8 + 7] * sc + sh;
  float* po = out + ((size_t)b * 32 + o) * NN + n0 + nseg * 8;
  *(float4*)po = a;
  *(float4*)(po + 4) = c;
}

// ---------------------------------------------------------------------------
extern "C" void kernel_launch(void* const* d_in, const int* in_sizes, int n_in,
                              void* d_out, int out_size, void* d_ws, size_t ws_size,
                              hipStream_t stream) {
  const float* x       = (const float*)d_in[0];
  const float* feature = (const float*)d_in[1];
  const float* g_w     = (const float*)d_in[2];
  const float* g_b     = (const float*)d_in[3];
  const float* theta_w = (const float*)d_in[4];
  const float* theta_b = (const float*)d_in[5];
  const float* phi_w   = (const float*)d_in[6];
  const float* phi_b   = (const float*)d_in[7];
  const float* W_w     = (const float*)d_in[8];
  const float* W_b     = (const float*)d_in[9];
  const float* bn_g    = (const float*)d_in[10];
  const float* bn_b    = (const float*)d_in[11];

  char* ws = (char*)d_ws;
  __hip_bfloat16* Theta    = (__hip_bfloat16*)(ws);                       // 4,718,592
  __hip_bfloat16* Gcm      = (__hip_bfloat16*)(ws + 4718592);             // 1,179,648
  __hip_bfloat16* PhiT     = (__hip_bfloat16*)(ws + 5898240);             // 1,179,648
  float*          z2       = (float*)(ws + 7077888);                      // 4,718,592
  __hip_bfloat16* ypart    = (__hip_bfloat16*)(ws + 11796480);            // 18,874,368
  float*          rsumpart = (float*)(ws + 30670848);                     // 589,824
  float*          psum     = (float*)(ws + 31260672);                     // 256

  conv_pool_k<<<dim3(288, NB), dim3(256), 0, stream>>>(
      x, feature, theta_w, theta_b, g_w, g_b, phi_w, phi_b, Theta, Gcm, PhiT, psum);
  attn_part<<<dim3(144 * MSPLIT, NB), dim3(256), 0, stream>>>(
      Theta, PhiT, Gcm, ypart, rsumpart);
  combine_k<<<dim3(144, NB), dim3(256), 0, stream>>>(
      ypart, rsumpart, x, W_w, W_b, z2, psum);
  bn_apply<<<dim3(144, NB), dim3(256), 0, stream>>>(
      z2, psum, bn_g, bn_b, (float*)d_out);
}